// Round 13
// baseline (7494.740 us; speedup 1.0000x reference)
//
#include <hip/hip_runtime.h>
#include <hip/hip_bf16.h>
#include <hip/hip_fp8.h>

typedef __attribute__((ext_vector_type(8))) short bh8;     // 8 bf16 (4 VGPRs)
typedef __attribute__((ext_vector_type(4))) float fx4;     // MFMA C/D
typedef __attribute__((ext_vector_type(4))) unsigned int ux4;
typedef unsigned int u32;
typedef unsigned long long u64;

#define S_LEN 2048
#define OUTBASE 16777216   // 8*2048*1024

__device__ __forceinline__ unsigned short f2bf(float f) {
  __hip_bfloat16 h = __float2bfloat16(f);
  unsigned short u; __builtin_memcpy(&u, &h, 2); return u;
}
__device__ __forceinline__ float bf2f(unsigned short u) {
  __hip_bfloat16 h; __builtin_memcpy(&h, &u, 2); return __bfloat162float(h);
}

// ---------------- prep: transpose + bf16-convert Wx for the big GEMM ----------------
__global__ __launch_bounds__(256) void prep_w(
    const float* __restrict__ Wi, const float* __restrict__ Wf,
    const float* __restrict__ Wg, const float* __restrict__ Wo,
    __hip_bfloat16* __restrict__ WxT) {
  __shared__ float tile[32][33];
  const int z = blockIdx.z;
  const float* src = (z==0)?Wi:(z==1)?Wf:(z==2)?Wg:Wo;
  const int kbase = blockIdx.y * 32, cbase = blockIdx.x * 32;
  const int tx = threadIdx.x, ty = threadIdx.y;
#pragma unroll
  for (int rr = 0; rr < 4; ++rr)
    tile[ty*4+rr][tx] = src[(size_t)(kbase + ty*4+rr)*1024 + cbase + tx];
  __syncthreads();
#pragma unroll
  for (int rr = 0; rr < 4; ++rr) {
    int c = cbase + ty*4+rr;
    int k = kbase + tx;
    WxT[(size_t)(z*1024 + c)*1024 + k] = __float2bfloat16(tile[tx][ty*4+rr]);
  }
}

// ------------- prep: gate-weight fp8 MFMA B-frags (Wh rows 1024..2047, x16 scale) ---
__global__ __launch_bounds__(128) void prep_gfrag8(
    const float* __restrict__ Wi, const float* __restrict__ Wf,
    const float* __restrict__ Wg, const float* __restrict__ Wo,
    unsigned char* __restrict__ gf8) {
  const int bx = blockIdx.x;                 // 4096 = 32 jb * 4 g * 32 k32
  const int jb = bx >> 7, g = (bx >> 5) & 3, k32 = bx & 31;
  const int tid = threadIdx.x, lane = tid & 63, ct = tid >> 6;
  const float* W = (g==0)?Wi:(g==1)?Wf:(g==2)?Wg:Wo;
  const int col = jb*32 + ct*16 + (lane & 15);
  const int kb = 1024 + k32*32 + ((lane >> 4) & 3)*8;
  unsigned char o[8];
#pragma unroll
  for (int i = 0; i < 8; ++i) {
    __hip_fp8_e4m3 q(W[(size_t)(kb + i)*1024 + col] * 16.0f);
    o[i] = q.__x;
  }
  u64 v; __builtin_memcpy(&v, o, 8);
  *reinterpret_cast<u64*>(gf8 + (size_t)jb*131072 +
                          (((g*2 + ct)*32 + k32)*512) + lane*8) = v;
}

// ---------------- prep: Weg fp8 MFMA B-fragments (x16 scale) ----------------
__global__ __launch_bounds__(128) void prep_wegfrag8(
    const float* __restrict__ Weg, unsigned char* __restrict__ wg8) {
  const int bx = blockIdx.x;                 // 1024 = 32 jb * 32 k32
  const int jb = bx >> 5, k32 = bx & 31;
  const int tid = threadIdx.x, lane = tid & 63, ct = tid >> 6;
  const int col = jb*32 + ct*16 + (lane & 15);
  const int kb = k32*32 + ((lane >> 4) & 3)*8;
  unsigned char o[8];
#pragma unroll
  for (int i = 0; i < 8; ++i) {
    __hip_fp8_e4m3 q(Weg[(size_t)(kb + i)*1024 + col] * 16.0f);
    o[i] = q.__x;
  }
  u64 v; __builtin_memcpy(&v, o, 8);
  *reinterpret_cast<u64*>(wg8 + (size_t)jb*32768 + ((k32*2 + ct)*512) + lane*8) = v;
}

// ---------------- init: zero tag buffers + team counters; bias concat ----------------
__global__ __launch_bounds__(256) void init_k(
    u32* h_tag, u32* g_tag, int* teamcnt,
    const float* __restrict__ bi, const float* __restrict__ bfv,
    const float* __restrict__ bg, const float* __restrict__ bo,
    float* __restrict__ bcat) {
  int t = blockIdx.x * 256 + threadIdx.x;
  if (t < 8192) { h_tag[t] = 0u; g_tag[t] = 0u; }   // value bf16(0), tag 0
  if (t < 32) teamcnt[t] = 0;
  if (t < 4096) {
    float v = (t < 1024) ? bi[t] : (t < 2048) ? bfv[t-1024]
            : (t < 3072) ? bg[t-2048] : bo[t-3072];
    bcat[t] = v;
  }
}

// ---------------- convert x to bf16 ----------------
__global__ __launch_bounds__(256) void conv_x(const float* __restrict__ x,
                                              __hip_bfloat16* __restrict__ xbf) {
  size_t i = ((size_t)blockIdx.x * 256 + threadIdx.x) * 8;
  fx4 a = *reinterpret_cast<const fx4*>(x + i);
  fx4 b = *reinterpret_cast<const fx4*>(x + i + 4);
  unsigned short o[8];
#pragma unroll
  for (int u = 0; u < 4; ++u) { o[u] = f2bf(a[u]); o[4+u] = f2bf(b[u]); }
  bh8 v; __builtin_memcpy(&v, o, 16);
  *reinterpret_cast<bh8*>(xbf + i) = v;
}

// ---------------- phase-1 GEMM: XG[s*8+b][c] = x @ Wx + bias (bf16) ----------------
__global__ __launch_bounds__(256) void gemm_x(
    const __hip_bfloat16* __restrict__ xbf,
    const __hip_bfloat16* __restrict__ WxT,
    const float* __restrict__ bcat,
    __hip_bfloat16* __restrict__ XG) {
  __shared__ bh8 ldsv[2048];                 // 32 KB
  char* lds = reinterpret_cast<char*>(ldsv);
  const int tid = threadIdx.x;
  const int bn = blockIdx.x, bm = blockIdx.y;
  const int lane = tid & 63, wid = tid >> 6;
  const int wr = wid >> 1, wc = wid & 1;
  fx4 acc[4][4] = {};
  for (int kb = 0; kb < 16; ++kb) {
    __syncthreads();
#pragma unroll
    for (int c = 0; c < 4; ++c) {
      int cid = tid + 256 * c;
      int r = cid >> 3, kc = cid & 7;
      bh8 va = *reinterpret_cast<const bh8*>(xbf + (size_t)(bm*128 + r)*1024 + kb*64 + kc*8);
      int off = (r*128 + kc*16) ^ ((r & 7) << 4);
      *reinterpret_cast<bh8*>(lds + off) = va;
      bh8 vb = *reinterpret_cast<const bh8*>(WxT + (size_t)(bn*128 + r)*1024 + kb*64 + kc*8);
      *reinterpret_cast<bh8*>(lds + 16384 + off) = vb;
    }
    __syncthreads();
#pragma unroll
    for (int ks = 0; ks < 2; ++ks) {
      bh8 af[4], bfr[4];
      int ac = ks*64 + (lane >> 4) * 16;
#pragma unroll
      for (int i = 0; i < 4; ++i) {
        int ar = wr*64 + i*16 + (lane & 15);
        af[i] = *reinterpret_cast<const bh8*>(lds + ((ar*128 + ac) ^ ((ar & 7) << 4)));
        int br = wc*64 + i*16 + (lane & 15);
        bfr[i] = *reinterpret_cast<const bh8*>(lds + 16384 + ((br*128 + ac) ^ ((br & 7) << 4)));
      }
#pragma unroll
      for (int i = 0; i < 4; ++i)
#pragma unroll
        for (int jn = 0; jn < 4; ++jn)
          acc[i][jn] = __builtin_amdgcn_mfma_f32_16x16x32_bf16(af[i], bfr[jn], acc[i][jn], 0, 0, 0);
    }
  }
#pragma unroll
  for (int i = 0; i < 4; ++i) {
    int rbase = bm*128 + wr*64 + i*16 + (lane >> 4) * 4;
#pragma unroll
    for (int jn = 0; jn < 4; ++jn) {
      int col = bn*128 + wc*64 + jn*16 + (lane & 15);
      float bias = bcat[col];
#pragma unroll
      for (int jj = 0; jj < 4; ++jj) {
        int r = rbase + jj;
        int b = r >> 11, s = r & 2047;
        XG[(size_t)(s*8 + b)*4096 + col] = __float2bfloat16(acc[i][jn][jj] + bias);
      }
    }
  }
}

// ---------------- poll primitives (sc01-only: the authoritative level) ----------------
__device__ __forceinline__ ux4 ld_sc01(const u32* p) {
  ux4 r;
  asm volatile("global_load_dwordx4 %0, %1, off sc0 sc1\n\ts_waitcnt vmcnt(0)"
               : "=v"(r) : "v"(p) : "memory");
  return r;
}
__device__ __forceinline__ u32 tagbad(ux4 v, u32 et) {
  return ((v.x ^ et) | (v.y ^ et) | (v.z ^ et) | (v.w ^ et)) & 0xffffu;
}
__device__ __forceinline__ u32 fp8pack4(ux4 v) {   // 4 bf16 (hi halves) -> 4 fp8
  __hip_fp8_e4m3 q0(bf2f((unsigned short)(v.x >> 16)));
  __hip_fp8_e4m3 q1(bf2f((unsigned short)(v.y >> 16)));
  __hip_fp8_e4m3 q2(bf2f((unsigned short)(v.z >> 16)));
  __hip_fp8_e4m3 q3(bf2f((unsigned short)(v.w >> 16)));
  return (u32)q0.__x | ((u32)q1.__x << 8) | ((u32)q2.__x << 16) | ((u32)q3.__x << 24);
}
__device__ __forceinline__ u32 pollpack(const u32* p, u32 etag) {
  ux4 v;
  while (true) {
    v = ld_sc01(p);
    if (!tagbad(v, etag)) break;
  }
  return fp8pack4(v);
}
__device__ __forceinline__ fx4 mfma8(u64 a, u64 b, fx4 c) {
  return __builtin_amdgcn_mfma_f32_16x16x32_fp8_fp8((long long)a, (long long)b, c, 0, 0, 0);
}

// -------- persistent recurrence: batch-per-XCD, g-first + overlapped h-link ---------
__global__ void __launch_bounds__(256, 1)
recur(const unsigned char* __restrict__ gf8, const unsigned char* __restrict__ wg8,
      const __hip_bfloat16* __restrict__ XG, const float* __restrict__ beg,
      u32* h_tag, u32* g_tag, int* teamcnt, float* d_out) {
  __shared__ unsigned char gw8[131072];      // 128 KB gate B-frags (fp8, x16)
  __shared__ unsigned char hstage8[1024];    // h vector, fp8 (written by waves 2,3)
  __shared__ unsigned char gstage8[1024];    // g vector, fp8 (all waves)
  __shared__ float pg[4][32];                // gate-g K-partials
  __shared__ float actp[4][3][32];           // i/f/o K-partials
  __shared__ float gact[32];                 // activated g (for c-state)
  __shared__ unsigned short xg_lds[2][128];  // XG slice dbuf [gate*32+col]
  __shared__ int sh_xid, sh_jb;

  const int tid = threadIdx.x;
  const int w = tid >> 6, lane = tid & 63, rgrp = lane >> 4;

  // rendezvous: team = physical XCD, role jb = claim order within team
  if (tid == 0) {
    u32 xid;
    asm volatile("s_getreg_b32 %0, hwreg(HW_REG_XCC_ID)" : "=s"(xid));
    sh_xid = (int)(xid & 7u);
    sh_jb = atomicAdd(&teamcnt[xid & 7u], 1) & 31;
  }
  __syncthreads();
  const int b = sh_xid, jb = sh_jb;          // batch b, owns h-cols [jb*32, jb*32+32)

  // one-time: 128 KB fp8 gate-weight fragments -> LDS
  {
    const ux4* src = reinterpret_cast<const ux4*>(gf8 + (size_t)jb*131072);
    ux4* dst = reinterpret_cast<ux4*>(gw8);
    for (int i = tid; i < 8192; i += 256) dst[i] = src[i];
  }
  // Weg fp8 fragments, FULL K for this wave's column half (used by waves 0,1)
  u64 wegr[32];
  {
    const int ct = w & 1;
#pragma unroll
    for (int q = 0; q < 32; ++q)
      wegr[q] = *reinterpret_cast<const u64*>(
          wg8 + (size_t)jb*32768 + ((q*2 + ct)*512) + lane*8);
  }

  float begv = 0.f, c_st = 0.f, n_st = 0.f;
  float i_v = 0.f, f_v = 0.f, o_v = 0.f, c_new = 0.f;
  if (w < 2 && lane < 16) begv = beg[jb*32 + w*16 + lane];
  if (tid < 32) {  // stage XG[0]  (layout gate*32+col)
    int gate = tid >> 3, chq = tid & 7;
    u64 v = *reinterpret_cast<const u64*>(
        &XG[((size_t)b)*4096 + gate*1024 + jb*32 + chq*4]);
    reinterpret_cast<u64*>(&xg_lds[0][0])[tid] = v;
  }
  if (tid < 128)   // h(0) = 0 -> fp8 0x00
    reinterpret_cast<u64*>(hstage8)[tid] = 0ull;
  __syncthreads();

#pragma unroll 1
  for (int t = 0; t < S_LEN; ++t) {
    __syncthreads();                         // B1: hstage(t) ready
    // A-fragments for this wave's K-quarter (shared by all 4 gates)
    u64 av[8];
#pragma unroll
    for (int q = 0; q < 8; ++q)
      av[q] = *reinterpret_cast<const u64*>(&hstage8[(w*8 + q)*32 + rgrp*8]);
    // ---- gate g FIRST (K-split over 4 waves, 16 MFMAs) ----
    fx4 ga0 = {0,0,0,0}, ga1 = {0,0,0,0};
#pragma unroll
    for (int q = 0; q < 8; ++q) {
      int k32 = w*8 + q;
      u64 b0 = *reinterpret_cast<const u64*>(&gw8[(4*32 + k32)*512 + lane*8]);
      u64 b1 = *reinterpret_cast<const u64*>(&gw8[(5*32 + k32)*512 + lane*8]);
      ga0 = mfma8(av[q], b0, ga0);
      ga1 = mfma8(av[q], b1, ga1);
    }
    if (lane < 16) { pg[w][lane] = ga0[0]; pg[w][16 + lane] = ga1[0]; }
    __syncthreads();                         // Bg: g partials ready
    if (tid < 32) {   // publish g ASAP; i/f/o MFMAs below cover the travel window
      int c = tid;
      float s = (pg[0][c] + pg[1][c] + pg[2][c] + pg[3][c])*0.0625f
              + bf2f(xg_lds[t & 1][64 + c]);
      float e2 = __expf(2.f*s);
      float gv = 1.f - 2.f/(e2 + 1.f);       // tanh
      gact[c] = gv;
      __hip_atomic_store(&g_tag[b*1024 + jb*32 + c],
                         ((u32)f2bf(gv) << 16) | (u32)(t + 1),
                         __ATOMIC_RELAXED, __HIP_MEMORY_SCOPE_AGENT);
    }
    // ---- gates i,f,o (K-split, 48 MFMAs — run inside g's visibility window) ----
    fx4 ai0={0,0,0,0}, ai1={0,0,0,0}, af0={0,0,0,0}, af1={0,0,0,0},
        ao0={0,0,0,0}, ao1={0,0,0,0};
#pragma unroll
    for (int q = 0; q < 8; ++q) {
      int k32 = w*8 + q;
      u64 bi0 = *reinterpret_cast<const u64*>(&gw8[(0*32 + k32)*512 + lane*8]);
      u64 bi1 = *reinterpret_cast<const u64*>(&gw8[(1*32 + k32)*512 + lane*8]);
      u64 bf0 = *reinterpret_cast<const u64*>(&gw8[(2*32 + k32)*512 + lane*8]);
      u64 bf1 = *reinterpret_cast<const u64*>(&gw8[(3*32 + k32)*512 + lane*8]);
      u64 bo0 = *reinterpret_cast<const u64*>(&gw8[(6*32 + k32)*512 + lane*8]);
      u64 bo1 = *reinterpret_cast<const u64*>(&gw8[(7*32 + k32)*512 + lane*8]);
      ai0 = mfma8(av[q], bi0, ai0);  ai1 = mfma8(av[q], bi1, ai1);
      af0 = mfma8(av[q], bf0, af0);  af1 = mfma8(av[q], bf1, af1);
      ao0 = mfma8(av[q], bo0, ao0);  ao1 = mfma8(av[q], bo1, ao1);
    }
    if (lane < 16) {
      actp[w][0][lane] = ai0[0];  actp[w][0][16 + lane] = ai1[0];
      actp[w][1][lane] = af0[0];  actp[w][1][16 + lane] = af1[0];
      actp[w][2][lane] = ao0[0];  actp[w][2][16 + lane] = ao1[0];
    }
    __syncthreads();                         // B2: i/f/o partials ready
    if (w < 2 && lane < 16) {                // act + c-state on owner lanes
      const int c = w*16 + lane;
      const unsigned short* xga = &xg_lds[t & 1][0];
      float pi = (actp[0][0][c] + actp[1][0][c] + actp[2][0][c] + actp[3][0][c])*0.0625f + bf2f(xga[c]);
      float pf = (actp[0][1][c] + actp[1][1][c] + actp[2][1][c] + actp[3][1][c])*0.0625f + bf2f(xga[32 + c]);
      float po = (actp[0][2][c] + actp[1][2][c] + actp[2][2][c] + actp[3][2][c])*0.0625f + bf2f(xga[96 + c]);
      i_v = 1.f / (1.f + __expf(-pi));
      f_v = 1.f / (1.f + __expf(-pf));
      o_v = 1.f / (1.f + __expf(-po));
      c_new = f_v * c_st + i_v * gact[c]; c_st = c_new;
    }
    // ---- all threads: poll g (tag t+1) — should hit on ~round 1 ----
    *reinterpret_cast<u32*>(&gstage8[tid*4]) =
        pollpack(g_tag + b*1024 + tid*4, (u32)(t + 1));
    __syncthreads();                         // B3: gstage ready
    if (w < 2) {
      // ==== finisher waves: phase B full-K for own 16 cols (32 MFMAs) ====
      fx4 eb[4] = {};
#pragma unroll
      for (int q = 0; q < 32; ++q) {
        u64 avb = *reinterpret_cast<const u64*>(&gstage8[q*32 + rgrp*8]);
        eb[q & 3] = mfma8(avb, wegr[q], eb[q & 3]);
      }
      if (lane < 16) {
        const int c = w*16 + lane;
        float e = (eb[0][0] + eb[1][0] + eb[2][0] + eb[3][0])*0.0625f + begv;
        float ex = __expf(e);
        float n_new = f_v * n_st + i_v * ex; n_st = n_new;
        float h_new = o_v * (c_new / n_new);
        if (t < S_LEN - 1)                   // publish h first (critical link)
          __hip_atomic_store(&h_tag[b*1024 + jb*32 + c],
                             ((u32)f2bf(h_new) << 16) | (u32)(t + 1),
                             __ATOMIC_RELAXED, __HIP_MEMORY_SCOPE_AGENT);
        d_out[((size_t)b*2048 + t)*1024 + jb*32 + c] = h_new;   // h history (pre-LN)
        if (t == S_LEN - 1) {
          d_out[OUTBASE +         (size_t)b*1024 + jb*32 + c] = h_new;  // h_f
          d_out[OUTBASE +  8192 + (size_t)b*1024 + jb*32 + c] = c_new;  // c_f
          d_out[OUTBASE + 16384 + (size_t)b*1024 + jb*32 + c] = n_new;  // n_f
        }
      }
    } else {
      // ==== poller waves (2,3): XG prefetch + poll h(t+1) into hstage ====
      const int idx = tid - 128;             // 0..127
      const int q32 = tid - 192;             // wave 3: 0..31 handle XG
      u64 xgv = 0;
      if (q32 >= 0 && q32 < 32 && t < S_LEN - 1) {
        int gate = q32 >> 3, chq = q32 & 7;
        xgv = *reinterpret_cast<const u64*>(
            &XG[((size_t)(t+1)*8 + b)*4096 + gate*1024 + jb*32 + chq*4]);
      }
      if (t < S_LEN - 1) {
        const u32* hp = h_tag + b*1024 + idx*8;
        const u32 et = (u32)(t + 1);
        ux4 v0, v1;
        while (true) {
          asm volatile("global_load_dwordx4 %0, %2, off sc0 sc1\n\t"
                       "global_load_dwordx4 %1, %2, off offset:16 sc0 sc1\n\t"
                       "s_waitcnt vmcnt(0)"
                       : "=&v"(v0), "=&v"(v1) : "v"(hp) : "memory");
          if (!(tagbad(v0, et) | tagbad(v1, et))) break;
        }
        u64 pk = (u64)fp8pack4(v0) | ((u64)fp8pack4(v1) << 32);
        *reinterpret_cast<u64*>(&hstage8[idx*8]) = pk;
      }
      if (q32 >= 0 && q32 < 32 && t < S_LEN - 1)
        reinterpret_cast<u64*>(&xg_lds[(t+1) & 1][0])[q32] = xgv;
    }
  }
}

// ---------------- residual + LayerNorm (in-place on d_out) ----------------
__global__ __launch_bounds__(256) void ln_k(const float* __restrict__ x,
                                            const float* __restrict__ gamma,
                                            const float* __restrict__ beta,
                                            float* __restrict__ out) {
  const int r = blockIdx.x, tid = threadIdx.x;
  float* orow = out + (size_t)r * 1024;
  const float* xrow = x + (size_t)r * 1024;
  fx4 h4 = *reinterpret_cast<const fx4*>(orow + tid*4);
  fx4 x4 = *reinterpret_cast<const fx4*>(xrow + tid*4);
  fx4 y = h4 + x4;
  float s = y[0] + y[1] + y[2] + y[3];
  float s2 = y[0]*y[0] + y[1]*y[1] + y[2]*y[2] + y[3]*y[3];
#pragma unroll
  for (int m = 1; m < 64; m <<= 1) { s += __shfl_xor(s, m, 64); s2 += __shfl_xor(s2, m, 64); }
  __shared__ float ps[4], ps2[4], stats[2];
  if ((tid & 63) == 0) { ps[tid >> 6] = s; ps2[tid >> 6] = s2; }
  __syncthreads();
  if (tid == 0) {
    float t1 = ps[0] + ps[1] + ps[2] + ps[3];
    float t2 = ps2[0] + ps2[1] + ps2[2] + ps2[3];
    float mu = t1 * (1.f / 1024.f);
    float var = t2 * (1.f / 1024.f) - mu * mu;
    stats[0] = mu; stats[1] = rsqrtf(var + 1e-5f);
  }
  __syncthreads();
  float mu = stats[0], rs = stats[1];
  fx4 g4 = *reinterpret_cast<const fx4*>(gamma + tid*4);
  fx4 b4 = *reinterpret_cast<const fx4*>(beta + tid*4);
  fx4 o4;
#pragma unroll
  for (int u = 0; u < 4; ++u) o4[u] = (y[u] - mu) * rs * g4[u] + b4[u];
  *reinterpret_cast<fx4*>(orow + tid*4) = o4;
}

extern "C" void kernel_launch(void* const* d_in, const int* in_sizes, int n_in,
                              void* d_out, int out_size, void* d_ws, size_t ws_size,
                              hipStream_t stream) {
  const float* x    = (const float*)d_in[0];
  const float* Wi   = (const float*)d_in[1];
  const float* bi   = (const float*)d_in[2];
  const float* Wf   = (const float*)d_in[3];
  const float* bfv  = (const float*)d_in[4];
  const float* Wg   = (const float*)d_in[5];
  const float* bg   = (const float*)d_in[6];
  const float* Wo   = (const float*)d_in[7];
  const float* bo   = (const float*)d_in[8];
  const float* Weg  = (const float*)d_in[9];
  const float* beg  = (const float*)d_in[10];
  const float* gamma= (const float*)d_in[11];
  const float* beta = (const float*)d_in[12];
  float* out = (float*)d_out;
  char* ws = (char*)d_ws;

  __hip_bfloat16* XG   = (__hip_bfloat16*)(ws);                    // 134217728 B
  __hip_bfloat16* xbf  = (__hip_bfloat16*)(ws + 134217728ull);     //  33554432 B
  __hip_bfloat16* WxT  = (__hip_bfloat16*)(ws + 167772160ull);     //   8388608 B
  unsigned char* gf8   = (unsigned char*)(ws + 176160768ull);      //   4194304 B
  unsigned char* wg8   = (unsigned char*)(ws + 184549376ull);      //   1048576 B
  float* bcat          = (float*)(ws + 186646528ull);              //     16384 B
  u32* h_tag           = (u32*)(ws + 186662912ull);                //     32768 B
  u32* g_tag           = (u32*)(ws + 186695680ull);                //     32768 B
  int* teamcnt         = (int*)(ws + 186728448ull);                //       128 B

  prep_w<<<dim3(32, 32, 4), dim3(32, 8), 0, stream>>>(Wi, Wf, Wg, Wo, WxT);
  prep_gfrag8<<<dim3(4096), dim3(128), 0, stream>>>(Wi, Wf, Wg, Wo, gf8);
  prep_wegfrag8<<<dim3(1024), dim3(128), 0, stream>>>(Weg, wg8);
  init_k<<<dim3(64), dim3(256), 0, stream>>>(h_tag, g_tag, teamcnt, bi, bfv, bg, bo, bcat);
  conv_x<<<dim3(8192), dim3(256), 0, stream>>>(x, xbf);
  gemm_x<<<dim3(32, 128), dim3(256), 0, stream>>>(xbf, WxT, bcat, XG);
  recur<<<dim3(256), dim3(256), 0, stream>>>(gf8, wg8, XG, beg, h_tag, g_tag, teamcnt, out);
  ln_k<<<dim3(16384), dim3(256), 0, stream>>>(x, gamma, beta, out);
}

// Round 14
// 7305.508 us; speedup vs baseline: 1.0259x; 1.0259x over previous
//
#include <hip/hip_runtime.h>
#include <hip/hip_bf16.h>
#include <hip/hip_fp8.h>

typedef __attribute__((ext_vector_type(8))) short bh8;     // 8 bf16 (4 VGPRs)
typedef __attribute__((ext_vector_type(4))) float fx4;     // MFMA C/D
typedef __attribute__((ext_vector_type(4))) unsigned int ux4;
typedef unsigned int u32;
typedef unsigned long long u64;

#define S_LEN 2048
#define OUTBASE 16777216   // 8*2048*1024

__device__ __forceinline__ unsigned short f2bf(float f) {
  __hip_bfloat16 h = __float2bfloat16(f);
  unsigned short u; __builtin_memcpy(&u, &h, 2); return u;
}
__device__ __forceinline__ float bf2f(unsigned short u) {
  __hip_bfloat16 h; __builtin_memcpy(&h, &u, 2); return __bfloat162float(h);
}

// ---------------- prep: transpose + bf16-convert Wx for the big GEMM ----------------
__global__ __launch_bounds__(256) void prep_w(
    const float* __restrict__ Wi, const float* __restrict__ Wf,
    const float* __restrict__ Wg, const float* __restrict__ Wo,
    __hip_bfloat16* __restrict__ WxT) {
  __shared__ float tile[32][33];
  const int z = blockIdx.z;
  const float* src = (z==0)?Wi:(z==1)?Wf:(z==2)?Wg:Wo;
  const int kbase = blockIdx.y * 32, cbase = blockIdx.x * 32;
  const int tx = threadIdx.x, ty = threadIdx.y;
#pragma unroll
  for (int rr = 0; rr < 4; ++rr)
    tile[ty*4+rr][tx] = src[(size_t)(kbase + ty*4+rr)*1024 + cbase + tx];
  __syncthreads();
#pragma unroll
  for (int rr = 0; rr < 4; ++rr) {
    int c = cbase + ty*4+rr;
    int k = kbase + tx;
    WxT[(size_t)(z*1024 + c)*1024 + k] = __float2bfloat16(tile[tx][ty*4+rr]);
  }
}

// ------------- prep: gate-weight fp8 MFMA B-frags (Wh rows 1024..2047, x16 scale) ---
__global__ __launch_bounds__(128) void prep_gfrag8(
    const float* __restrict__ Wi, const float* __restrict__ Wf,
    const float* __restrict__ Wg, const float* __restrict__ Wo,
    unsigned char* __restrict__ gf8) {
  const int bx = blockIdx.x;                 // 4096 = 32 jb * 4 g * 32 k32
  const int jb = bx >> 7, g = (bx >> 5) & 3, k32 = bx & 31;
  const int tid = threadIdx.x, lane = tid & 63, ct = tid >> 6;
  const float* W = (g==0)?Wi:(g==1)?Wf:(g==2)?Wg:Wo;
  const int col = jb*32 + ct*16 + (lane & 15);
  const int kb = 1024 + k32*32 + ((lane >> 4) & 3)*8;
  unsigned char o[8];
#pragma unroll
  for (int i = 0; i < 8; ++i) {
    __hip_fp8_e4m3 q(W[(size_t)(kb + i)*1024 + col] * 16.0f);
    o[i] = q.__x;
  }
  u64 v; __builtin_memcpy(&v, o, 8);
  *reinterpret_cast<u64*>(gf8 + (size_t)jb*131072 +
                          (((g*2 + ct)*32 + k32)*512) + lane*8) = v;
}

// ---------------- prep: Weg fp8 MFMA B-fragments (x16 scale) ----------------
__global__ __launch_bounds__(128) void prep_wegfrag8(
    const float* __restrict__ Weg, unsigned char* __restrict__ wg8) {
  const int bx = blockIdx.x;                 // 1024 = 32 jb * 32 k32
  const int jb = bx >> 5, k32 = bx & 31;
  const int tid = threadIdx.x, lane = tid & 63, ct = tid >> 6;
  const int col = jb*32 + ct*16 + (lane & 15);
  const int kb = k32*32 + ((lane >> 4) & 3)*8;
  unsigned char o[8];
#pragma unroll
  for (int i = 0; i < 8; ++i) {
    __hip_fp8_e4m3 q(Weg[(size_t)(kb + i)*1024 + col] * 16.0f);
    o[i] = q.__x;
  }
  u64 v; __builtin_memcpy(&v, o, 8);
  *reinterpret_cast<u64*>(wg8 + (size_t)jb*32768 + ((k32*2 + ct)*512) + lane*8) = v;
}

// ---------------- init: zero tag buffers + team counters; bias concat ----------------
__global__ __launch_bounds__(256) void init_k(
    u32* h_tag, u32* g_tag, int* teamcnt,
    const float* __restrict__ bi, const float* __restrict__ bfv,
    const float* __restrict__ bg, const float* __restrict__ bo,
    float* __restrict__ bcat) {
  int t = blockIdx.x * 256 + threadIdx.x;
  if (t < 8192) { h_tag[t] = 0u; g_tag[t] = 0u; }   // value bf16(0), tag 0
  if (t < 32) teamcnt[t] = 0;
  if (t < 4096) {
    float v = (t < 1024) ? bi[t] : (t < 2048) ? bfv[t-1024]
            : (t < 3072) ? bg[t-2048] : bo[t-3072];
    bcat[t] = v;
  }
}

// ---------------- convert x to bf16 ----------------
__global__ __launch_bounds__(256) void conv_x(const float* __restrict__ x,
                                              __hip_bfloat16* __restrict__ xbf) {
  size_t i = ((size_t)blockIdx.x * 256 + threadIdx.x) * 8;
  fx4 a = *reinterpret_cast<const fx4*>(x + i);
  fx4 b = *reinterpret_cast<const fx4*>(x + i + 4);
  unsigned short o[8];
#pragma unroll
  for (int u = 0; u < 4; ++u) { o[u] = f2bf(a[u]); o[4+u] = f2bf(b[u]); }
  bh8 v; __builtin_memcpy(&v, o, 16);
  *reinterpret_cast<bh8*>(xbf + i) = v;
}

// ---------------- phase-1 GEMM: XG[s*8+b][c] = x @ Wx + bias (bf16) ----------------
__global__ __launch_bounds__(256) void gemm_x(
    const __hip_bfloat16* __restrict__ xbf,
    const __hip_bfloat16* __restrict__ WxT,
    const float* __restrict__ bcat,
    __hip_bfloat16* __restrict__ XG) {
  __shared__ bh8 ldsv[2048];                 // 32 KB
  char* lds = reinterpret_cast<char*>(ldsv);
  const int tid = threadIdx.x;
  const int bn = blockIdx.x, bm = blockIdx.y;
  const int lane = tid & 63, wid = tid >> 6;
  const int wr = wid >> 1, wc = wid & 1;
  fx4 acc[4][4] = {};
  for (int kb = 0; kb < 16; ++kb) {
    __syncthreads();
#pragma unroll
    for (int c = 0; c < 4; ++c) {
      int cid = tid + 256 * c;
      int r = cid >> 3, kc = cid & 7;
      bh8 va = *reinterpret_cast<const bh8*>(xbf + (size_t)(bm*128 + r)*1024 + kb*64 + kc*8);
      int off = (r*128 + kc*16) ^ ((r & 7) << 4);
      *reinterpret_cast<bh8*>(lds + off) = va;
      bh8 vb = *reinterpret_cast<const bh8*>(WxT + (size_t)(bn*128 + r)*1024 + kb*64 + kc*8);
      *reinterpret_cast<bh8*>(lds + 16384 + off) = vb;
    }
    __syncthreads();
#pragma unroll
    for (int ks = 0; ks < 2; ++ks) {
      bh8 af[4], bfr[4];
      int ac = ks*64 + (lane >> 4) * 16;
#pragma unroll
      for (int i = 0; i < 4; ++i) {
        int ar = wr*64 + i*16 + (lane & 15);
        af[i] = *reinterpret_cast<const bh8*>(lds + ((ar*128 + ac) ^ ((ar & 7) << 4)));
        int br = wc*64 + i*16 + (lane & 15);
        bfr[i] = *reinterpret_cast<const bh8*>(lds + 16384 + ((br*128 + ac) ^ ((br & 7) << 4)));
      }
#pragma unroll
      for (int i = 0; i < 4; ++i)
#pragma unroll
        for (int jn = 0; jn < 4; ++jn)
          acc[i][jn] = __builtin_amdgcn_mfma_f32_16x16x32_bf16(af[i], bfr[jn], acc[i][jn], 0, 0, 0);
    }
  }
#pragma unroll
  for (int i = 0; i < 4; ++i) {
    int rbase = bm*128 + wr*64 + i*16 + (lane >> 4) * 4;
#pragma unroll
    for (int jn = 0; jn < 4; ++jn) {
      int col = bn*128 + wc*64 + jn*16 + (lane & 15);
      float bias = bcat[col];
#pragma unroll
      for (int jj = 0; jj < 4; ++jj) {
        int r = rbase + jj;
        int b = r >> 11, s = r & 2047;
        XG[(size_t)(s*8 + b)*4096 + col] = __float2bfloat16(acc[i][jn][jj] + bias);
      }
    }
  }
}

// ---------------- poll primitives ----------------
// sc1 = AGENT scope — the scope __hip_atomic_store(AGENT) publishes at
// (gfx940+ encoding: sc0 = workgroup [can hit own L1, stale], sc1 = agent,
//  sc0 sc1 = system). Agent loads are HW-guaranteed to see agent stores.
__device__ __forceinline__ ux4 ld_sc1(const u32* p) {
  ux4 r;
  asm volatile("global_load_dwordx4 %0, %1, off sc1\n\ts_waitcnt vmcnt(0)"
               : "=v"(r) : "v"(p) : "memory");
  return r;
}
__device__ __forceinline__ ux4 ld_sc01(const u32* p) {   // system-scope escape
  ux4 r;
  asm volatile("global_load_dwordx4 %0, %1, off sc0 sc1\n\ts_waitcnt vmcnt(0)"
               : "=v"(r) : "v"(p) : "memory");
  return r;
}
__device__ __forceinline__ u32 tagbad(ux4 v, u32 et) {
  return ((v.x ^ et) | (v.y ^ et) | (v.z ^ et) | (v.w ^ et)) & 0xffffu;
}
__device__ __forceinline__ u32 fp8pack4(ux4 v) {   // 4 bf16 (hi halves) -> 4 fp8
  __hip_fp8_e4m3 q0(bf2f((unsigned short)(v.x >> 16)));
  __hip_fp8_e4m3 q1(bf2f((unsigned short)(v.y >> 16)));
  __hip_fp8_e4m3 q2(bf2f((unsigned short)(v.z >> 16)));
  __hip_fp8_e4m3 q3(bf2f((unsigned short)(v.w >> 16)));
  return (u32)q0.__x | ((u32)q1.__x << 8) | ((u32)q2.__x << 16) | ((u32)q3.__x << 24);
}
// poll until all 4 tags match: agent-scope rounds, system-scope every 8th
// (insurance only — never fires if sc1 observes agent stores as architected).
__device__ __forceinline__ u32 pollpack(const u32* p, u32 etag) {
  ux4 v; int rnd = 0;
  while (true) {
    v = ((rnd & 7) != 7) ? ld_sc1(p) : ld_sc01(p);
    ++rnd;
    if (!tagbad(v, etag)) break;
  }
  return fp8pack4(v);
}
__device__ __forceinline__ fx4 mfma8(u64 a, u64 b, fx4 c) {
  return __builtin_amdgcn_mfma_f32_16x16x32_fp8_fp8((long long)a, (long long)b, c, 0, 0, 0);
}

// -------- persistent recurrence: batch-per-XCD, fp8 weights fully LDS-resident ------
__global__ void __launch_bounds__(256, 1)
recur(const unsigned char* __restrict__ gf8, const unsigned char* __restrict__ wg8,
      const __hip_bfloat16* __restrict__ XG, const float* __restrict__ beg,
      u32* h_tag, u32* g_tag, int* teamcnt, float* d_out) {
  __shared__ unsigned char gw8[131072];      // 128 KB gate B-frags (fp8, x16)
  __shared__ unsigned char hstage8[1024];    // h vector, fp8
  __shared__ unsigned char gstage8[1024];    // g vector, fp8
  __shared__ float act_lds[128];             // phase-A D row0 per gate
  __shared__ float exk[128];                 // phase-B K-split partials
  __shared__ unsigned short xg_lds[2][128];  // XG slice dbuf [gate*32+col]
  __shared__ int sh_xid, sh_jb;

  const int tid = threadIdx.x;
  const int w = tid >> 6, lane = tid & 63, rgrp = lane >> 4;

  // rendezvous: team = physical XCD, role jb = claim order within team
  if (tid == 0) {
    u32 xid;
    asm volatile("s_getreg_b32 %0, hwreg(HW_REG_XCC_ID)" : "=s"(xid));
    sh_xid = (int)(xid & 7u);
    sh_jb = atomicAdd(&teamcnt[xid & 7u], 1) & 31;
  }
  __syncthreads();
  const int b = sh_xid, jb = sh_jb;          // batch b, owns h-cols [jb*32, jb*32+32)

  // one-time: 128 KB fp8 gate-weight fragments -> LDS
  {
    const ux4* src = reinterpret_cast<const ux4*>(gf8 + (size_t)jb*131072);
    ux4* dst = reinterpret_cast<ux4*>(gw8);
    for (int i = tid; i < 8192; i += 256) dst[i] = src[i];
  }
  // Weg fp8 fragments -> VGPR (16 u64 = 32 VGPRs)
  u64 wegr[16];
#pragma unroll
  for (int q = 0; q < 8; ++q)
#pragma unroll
    for (int ct = 0; ct < 2; ++ct)
      wegr[q*2 + ct] = *reinterpret_cast<const u64*>(
          wg8 + (size_t)jb*32768 + (((w*8 + q)*2 + ct)*512) + lane*8);

  float begv = 0.f, c_st = 0.f, n_st = 0.f;
  float i_v = 0.f, f_v = 0.f, o_v = 0.f, c_new = 0.f;
  if (tid < 32) begv = beg[jb*32 + tid];
  if (tid < 32) {  // stage XG[0]  (layout gate*32+col)
    int gate = tid >> 3, ch = tid & 7;
    u64 v = *reinterpret_cast<const u64*>(
        &XG[((size_t)b)*4096 + gate*1024 + jb*32 + ch*4]);
    reinterpret_cast<u64*>(&xg_lds[0][0])[tid] = v;
  }
  __syncthreads();

#pragma unroll 1
  for (int t = 0; t < S_LEN; ++t) {
    // ---- poll h (tag t), stage as fp8 ----
    *reinterpret_cast<u32*>(&hstage8[tid*4]) =
        pollpack(h_tag + b*1024 + tid*4, (u32)t);
    // issue next-step XG loads AFTER the poll (so the poll's vmcnt never
    // drains this HBM load); landed just before the g-poll, hidden under
    // phase A's 64 MFMAs.
    u64 xgv = 0;
    const int q32 = tid - 192;
    if (q32 >= 0 && q32 < 32 && t < S_LEN - 1) {
      int gate = q32 >> 3, ch = q32 & 7;
      xgv = *reinterpret_cast<const u64*>(
          &XG[((size_t)(t+1)*8 + b)*4096 + gate*1024 + jb*32 + ch*4]);
    }
    __syncthreads();                         // B1: hstage ready
    // ---- phase A: wave w -> gate w, 32 cols, K=1024 (fp8 MFMA, all from LDS) ----
    fx4 a00 = {0,0,0,0}, a01 = {0,0,0,0}, a10 = {0,0,0,0}, a11 = {0,0,0,0};
#pragma unroll
    for (int k32 = 0; k32 < 32; ++k32) {
      u64 av = *reinterpret_cast<const u64*>(&hstage8[k32*32 + rgrp*8]);
      u64 b0 = *reinterpret_cast<const u64*>(&gw8[(((w*2 + 0)*32 + k32)*512) + lane*8]);
      u64 b1 = *reinterpret_cast<const u64*>(&gw8[(((w*2 + 1)*32 + k32)*512) + lane*8]);
      if (k32 & 1) {
        a10 = mfma8(av, b0, a10);
        a11 = mfma8(av, b1, a11);
      } else {
        a00 = mfma8(av, b0, a00);
        a01 = mfma8(av, b1, a01);
      }
    }
    if (lane < 16) {                          // D row 0 = lanes 0-15, reg 0
      act_lds[w*32 + lane]      = a00[0] + a10[0];
      act_lds[w*32 + 16 + lane] = a01[0] + a11[0];
    }
    __syncthreads();                         // B2: preacts ready
    if (tid < 32) {   // gates + c-state; publish g ASAP (1/16 un-scale)
      int c = tid;
      const unsigned short* xga = &xg_lds[t & 1][0];
      float pg = act_lds[64 + c]*0.0625f + bf2f(xga[64 + c]);
      float e2 = __expf(2.f*pg);
      float g_v = 1.f - 2.f/(e2 + 1.f);      // tanh
      __hip_atomic_store(&g_tag[b*1024 + jb*32 + c],
                         ((u32)f2bf(g_v) << 16) | (u32)(t + 1),
                         __ATOMIC_RELAXED, __HIP_MEMORY_SCOPE_AGENT);
      float pi = act_lds[c]*0.0625f      + bf2f(xga[c]);
      float pf = act_lds[32 + c]*0.0625f + bf2f(xga[32 + c]);
      float po = act_lds[96 + c]*0.0625f + bf2f(xga[96 + c]);
      i_v = 1.f / (1.f + __expf(-pi));
      f_v = 1.f / (1.f + __expf(-pf));
      o_v = 1.f / (1.f + __expf(-po));
      c_new = f_v * c_st + i_v * g_v; c_st = c_new;
    }
    if (q32 >= 0 && q32 < 32 && t < S_LEN - 1)   // land XG prefetch (load long done)
      reinterpret_cast<u64*>(&xg_lds[(t+1) & 1][0])[q32] = xgv;
    // ---- poll g (tag t+1), stage as fp8 ----
    *reinterpret_cast<u32*>(&gstage8[tid*4]) =
        pollpack(g_tag + b*1024 + tid*4, (u32)(t + 1));
    __syncthreads();                         // B3: gstage ready
    // ---- phase B: e = g @ Weg, K split across 4 waves (fp8) ----
    fx4 e00={0,0,0,0}, e01={0,0,0,0}, e10={0,0,0,0}, e11={0,0,0,0};
#pragma unroll
    for (int q = 0; q < 8; ++q) {
      u64 av = *reinterpret_cast<const u64*>(&gstage8[w*256 + q*32 + rgrp*8]);
      if (q & 1) {
        e10 = mfma8(av, wegr[q*2],     e10);
        e11 = mfma8(av, wegr[q*2 + 1], e11);
      } else {
        e00 = mfma8(av, wegr[q*2],     e00);
        e01 = mfma8(av, wegr[q*2 + 1], e01);
      }
    }
    if (lane < 16) {
      exk[w*32 + lane]      = e00[0] + e10[0];
      exk[w*32 + 16 + lane] = e01[0] + e11[0];
    }
    __syncthreads();                         // B4: exk ready
    if (tid < 32) {
      float s = (exk[tid] + exk[32 + tid] + exk[64 + tid] + exk[96 + tid])*0.0625f + begv;
      float e = __expf(s);
      float n_new = f_v * n_st + i_v * e; n_st = n_new;
      float h_new = o_v * (c_new / n_new);
      if (t < S_LEN - 1)                     // publish h first (critical)
        __hip_atomic_store(&h_tag[b*1024 + jb*32 + tid],
                           ((u32)f2bf(h_new) << 16) | (u32)(t + 1),
                           __ATOMIC_RELAXED, __HIP_MEMORY_SCOPE_AGENT);
      d_out[((size_t)b*2048 + t)*1024 + jb*32 + tid] = h_new;   // h history (pre-LN)
      if (t == S_LEN - 1) {
        d_out[OUTBASE +         (size_t)b*1024 + jb*32 + tid] = h_new;  // h_f
        d_out[OUTBASE +  8192 + (size_t)b*1024 + jb*32 + tid] = c_new;  // c_f
        d_out[OUTBASE + 16384 + (size_t)b*1024 + jb*32 + tid] = n_new;  // n_f
      }
    }
  }
}

// ---------------- residual + LayerNorm (in-place on d_out) ----------------
__global__ __launch_bounds__(256) void ln_k(const float* __restrict__ x,
                                            const float* __restrict__ gamma,
                                            const float* __restrict__ beta,
                                            float* __restrict__ out) {
  const int r = blockIdx.x, tid = threadIdx.x;
  float* orow = out + (size_t)r * 1024;
  const float* xrow = x + (size_t)r * 1024;
  fx4 h4 = *reinterpret_cast<const fx4*>(orow + tid*4);
  fx4 x4 = *reinterpret_cast<const fx4*>(xrow + tid*4);
  fx4 y = h4 + x4;
  float s = y[0] + y[1] + y[2] + y[3];
  float s2 = y[0]*y[0] + y[1]*y[1] + y[2]*y[2] + y[3]*y[3];
#pragma unroll
  for (int m = 1; m < 64; m <<= 1) { s += __shfl_xor(s, m, 64); s2 += __shfl_xor(s2, m, 64); }
  __shared__ float ps[4], ps2[4], stats[2];
  if ((tid & 63) == 0) { ps[tid >> 6] = s; ps2[tid >> 6] = s2; }
  __syncthreads();
  if (tid == 0) {
    float t1 = ps[0] + ps[1] + ps[2] + ps[3];
    float t2 = ps2[0] + ps2[1] + ps2[2] + ps2[3];
    float mu = t1 * (1.f / 1024.f);
    float var = t2 * (1.f / 1024.f) - mu * mu;
    stats[0] = mu; stats[1] = rsqrtf(var + 1e-5f);
  }
  __syncthreads();
  float mu = stats[0], rs = stats[1];
  fx4 g4 = *reinterpret_cast<const fx4*>(gamma + tid*4);
  fx4 b4 = *reinterpret_cast<const fx4*>(beta + tid*4);
  fx4 o4;
#pragma unroll
  for (int u = 0; u < 4; ++u) o4[u] = (y[u] - mu) * rs * g4[u] + b4[u];
  *reinterpret_cast<fx4*>(orow + tid*4) = o4;
}

extern "C" void kernel_launch(void* const* d_in, const int* in_sizes, int n_in,
                              void* d_out, int out_size, void* d_ws, size_t ws_size,
                              hipStream_t stream) {
  const float* x    = (const float*)d_in[0];
  const float* Wi   = (const float*)d_in[1];
  const float* bi   = (const float*)d_in[2];
  const float* Wf   = (const float*)d_in[3];
  const float* bfv  = (const float*)d_in[4];
  const float* Wg   = (const float*)d_in[5];
  const float* bg   = (const float*)d_in[6];
  const float* Wo   = (const float*)d_in[7];
  const float* bo   = (const float*)d_in[8];
  const float* Weg  = (const float*)d_in[9];
  const float* beg  = (const float*)d_in[10];
  const float* gamma= (const float*)d_in[11];
  const float* beta = (const float*)d_in[12];
  float* out = (float*)d_out;
  char* ws = (char*)d_ws;

  __hip_bfloat16* XG   = (__hip_bfloat16*)(ws);                    // 134217728 B
  __hip_bfloat16* xbf  = (__hip_bfloat16*)(ws + 134217728ull);     //  33554432 B
  __hip_bfloat16* WxT  = (__hip_bfloat16*)(ws + 167772160ull);     //   8388608 B
  unsigned char* gf8   = (unsigned char*)(ws + 176160768ull);      //   4194304 B
  unsigned char* wg8   = (unsigned char*)(ws + 184549376ull);      //   1048576 B
  float* bcat          = (float*)(ws + 186646528ull);              //     16384 B
  u32* h_tag           = (u32*)(ws + 186662912ull);                //     32768 B
  u32* g_tag           = (u32*)(ws + 186695680ull);                //     32768 B
  int* teamcnt         = (int*)(ws + 186728448ull);                //       128 B

  prep_w<<<dim3(32, 32, 4), dim3(32, 8), 0, stream>>>(Wi, Wf, Wg, Wo, WxT);
  prep_gfrag8<<<dim3(4096), dim3(128), 0, stream>>>(Wi, Wf, Wg, Wo, gf8);
  prep_wegfrag8<<<dim3(1024), dim3(128), 0, stream>>>(Weg, wg8);
  init_k<<<dim3(64), dim3(256), 0, stream>>>(h_tag, g_tag, teamcnt, bi, bfv, bg, bo, bcat);
  conv_x<<<dim3(8192), dim3(256), 0, stream>>>(x, xbf);
  gemm_x<<<dim3(32, 128), dim3(256), 0, stream>>>(xbf, WxT, bcat, XG);
  recur<<<dim3(256), dim3(256), 0, stream>>>(gf8, wg8, XG, beg, h_tag, g_tag, teamcnt, out);
  ln_k<<<dim3(16384), dim3(256), 0, stream>>>(x, gamma, beta, out);
}